// Round 3
// baseline (262.523 us; speedup 1.0000x reference)
//
#include <hip/hip_runtime.h>

#define CUBE_LEN   512
#define EQU_H      1024
#define EQU_W      2048
#define EQU_COUNT  4
#define CHANNELS   3

// One thread per equirect pixel (h,w). Reads uv (float2) + face once,
// then produces all E*C = 12 outputs for that pixel via 4-tap bilinear
// gathers from the selected cube face. LUT read exactly once; writes
// coalesced in w within each (e,c) plane, streamed non-temporally so the
// 100 MB write-once output doesn't evict the gather working set from L2/L3.
__global__ __launch_bounds__(256) void cube2equirec_kernel(
    const float* __restrict__ x,
    const float* __restrict__ uv,
    const int*   __restrict__ face,
    float*       __restrict__ out)
{
    const int HW  = EQU_H * EQU_W;          // 1 << 21
    const int idx = blockIdx.x * blockDim.x + threadIdx.x;
    if (idx >= HW) return;

    const float2 uvv = ((const float2*)uv)[idx];
    const float u = uvv.x;
    const float v = uvv.y;
    const int   f = face[idx];

    int x0 = (int)floorf(u);
    int y0 = (int)floorf(v);
    x0 = min(max(x0, 0), CUBE_LEN - 1);
    y0 = min(max(y0, 0), CUBE_LEN - 1);
    const int x1 = min(x0 + 1, CUBE_LEN - 1);
    const int y1 = min(y0 + 1, CUBE_LEN - 1);

    const float wx = u - (float)x0;
    const float wy = v - (float)y0;
    const float w00 = (1.0f - wx) * (1.0f - wy);
    const float w01 = wx * (1.0f - wy);
    const float w10 = (1.0f - wx) * wy;
    const float w11 = wx * wy;

    const int o00 = y0 * CUBE_LEN + x0;
    const int o01 = y0 * CUBE_LEN + x1;
    const int o10 = y1 * CUBE_LEN + x0;
    const int o11 = y1 * CUBE_LEN + x1;

    const int PLANE = CUBE_LEN * CUBE_LEN;   // 262144
    const int IMG   = CHANNELS * PLANE;      // 786432

#pragma unroll
    for (int e = 0; e < EQU_COUNT; ++e) {
        const int img_base = (e * 6 + f) * IMG;   // max ~18.1M, fits int32
#pragma unroll
        for (int c = 0; c < CHANNELS; ++c) {
            const float* __restrict__ p = x + img_base + c * PLANE;
            const float val = p[o00] * w00 + p[o01] * w01
                            + p[o10] * w10 + p[o11] * w11;
            __builtin_nontemporal_store(val, &out[(e * CHANNELS + c) * HW + idx]);
        }
    }
}

extern "C" void kernel_launch(void* const* d_in, const int* in_sizes, int n_in,
                              void* d_out, int out_size, void* d_ws, size_t ws_size,
                              hipStream_t stream) {
    const float* x    = (const float*)d_in[0];
    const float* uv   = (const float*)d_in[1];
    const int*   face = (const int*)d_in[2];
    float*       out  = (float*)d_out;

    const int HW = EQU_H * EQU_W;
    const int block = 256;
    const int grid  = (HW + block - 1) / block;  // 8192 blocks

    hipLaunchKernelGGL(cube2equirec_kernel, dim3(grid), dim3(block), 0, stream,
                       x, uv, face, out);
}

// Round 6
// 234.335 us; speedup vs baseline: 1.1203x; 1.1203x over previous
//
#include <hip/hip_runtime.h>

#define CUBE_LEN   512
#define EQU_H      1024
#define EQU_W      2048
#define EQU_COUNT  4
#define CHANNELS   3

// One thread per equirect pixel (h,w). Re-parameterized bilinear taps:
//   x0 = clamp(floor(u), 0, 510), wx = u - x0  (wx==1 when u==511)
// makes x1 = x0+1 ALWAYS, so the four taps are two adjacent pairs.
// All 48 gather loads are issued into register arrays BEFORE any use,
// giving ~48 outstanding loads/thread to hide gather latency (round-3
// profile showed latency-bound: 1.1 TB/s HBM, VALUBusy 7%, VGPR=36).
__global__ __launch_bounds__(256) void cube2equirec_kernel(
    const float* __restrict__ x,
    const float* __restrict__ uv,
    const int*   __restrict__ face,
    float*       __restrict__ out)
{
    const int HW  = EQU_H * EQU_W;          // 1 << 21
    const int idx = blockIdx.x * blockDim.x + threadIdx.x;
    if (idx >= HW) return;

    const float2 uvv = ((const float2*)uv)[idx];
    const float u = uvv.x;
    const float v = uvv.y;
    const int   f = face[idx];

    int x0 = (int)floorf(u);
    int y0 = (int)floorf(v);
    x0 = min(max(x0, 0), CUBE_LEN - 2);     // 0..510
    y0 = min(max(y0, 0), CUBE_LEN - 2);

    const float wx = u - (float)x0;         // in [0,1]
    const float wy = v - (float)y0;

    const int o00 = y0 * CUBE_LEN + x0;     // (y0, x0)
    const int o10 = o00 + CUBE_LEN;         // (y0+1, x0)

    const int PLANE = CUBE_LEN * CUBE_LEN;  // 262144
    const int IMG   = CHANNELS * PLANE;     // 786432

    // ---- batch all gather loads (independent, maximal MLP) ----
    float a00[EQU_COUNT * CHANNELS], a01[EQU_COUNT * CHANNELS];
    float a10[EQU_COUNT * CHANNELS], a11[EQU_COUNT * CHANNELS];
#pragma unroll
    for (int e = 0; e < EQU_COUNT; ++e) {
        const int img_base = (e * 6 + f) * IMG;   // max ~18.1M floats
#pragma unroll
        for (int c = 0; c < CHANNELS; ++c) {
            const float* __restrict__ p = x + img_base + c * PLANE;
            const int i = e * CHANNELS + c;
            a00[i] = p[o00];
            a01[i] = p[o00 + 1];
            a10[i] = p[o10];
            a11[i] = p[o10 + 1];
        }
    }

    // ---- compute + store ----
    const float w00 = (1.0f - wx) * (1.0f - wy);
    const float w01 = wx * (1.0f - wy);
    const float w10 = (1.0f - wx) * wy;
    const float w11 = wx * wy;

#pragma unroll
    for (int i = 0; i < EQU_COUNT * CHANNELS; ++i) {
        const float val = a00[i] * w00 + a01[i] * w01
                        + a10[i] * w10 + a11[i] * w11;
        __builtin_nontemporal_store(val, &out[i * HW + idx]);
    }
}

extern "C" void kernel_launch(void* const* d_in, const int* in_sizes, int n_in,
                              void* d_out, int out_size, void* d_ws, size_t ws_size,
                              hipStream_t stream) {
    const float* x    = (const float*)d_in[0];
    const float* uv   = (const float*)d_in[1];
    const int*   face = (const int*)d_in[2];
    float*       out  = (float*)d_out;

    const int HW = EQU_H * EQU_W;
    const int block = 256;
    const int grid  = (HW + block - 1) / block;  // 8192 blocks

    hipLaunchKernelGGL(cube2equirec_kernel, dim3(grid), dim3(block), 0, stream,
                       x, uv, face, out);
}

// Round 7
// 221.762 us; speedup vs baseline: 1.1838x; 1.0567x over previous
//
#include <hip/hip_runtime.h>

#define CUBE_LEN   512
#define EQU_H      1024
#define EQU_W      2048
#define EQU_COUNT  4
#define CHANNELS   3

// One thread per equirect pixel (h,w). Bilinear taps re-parameterized:
//   x0 = clamp(floor(u), 0, 510), wx = u - x0  (wx==1 when u==511)
// so x1 = x0+1 always -> each row's two taps are adjacent.
//
// Round-6 post-mortem: compiler sank the batched loads (VGPR=36 -> ~6
// in-flight vmem/CU, 51 cyc/vmem-instr, latency-bound at 1.4 TB/s).
// Fix: __launch_bounds__(256,1) lifts the register budget (110 VGPR still
// gives 5 waves/SIMD = measured occupancy) and sched_barrier(0) pins all
// 48 gather loads above the compute so they are all in flight at once.
__global__ __launch_bounds__(256, 1) void cube2equirec_kernel(
    const float* __restrict__ x,
    const float* __restrict__ uv,
    const int*   __restrict__ face,
    float*       __restrict__ out)
{
    const int HW  = EQU_H * EQU_W;          // 1 << 21
    const int idx = blockIdx.x * blockDim.x + threadIdx.x;
    if (idx >= HW) return;

    const float2 uvv = ((const float2*)uv)[idx];
    const float u = uvv.x;
    const float v = uvv.y;
    const int   f = face[idx];

    int x0 = (int)floorf(u);
    int y0 = (int)floorf(v);
    x0 = min(max(x0, 0), CUBE_LEN - 2);     // 0..510
    y0 = min(max(y0, 0), CUBE_LEN - 2);

    const float wx = u - (float)x0;         // in [0,1]
    const float wy = v - (float)y0;

    const int o00 = y0 * CUBE_LEN + x0;     // (y0, x0)
    const int o10 = o00 + CUBE_LEN;         // (y0+1, x0)

    const int PLANE = CUBE_LEN * CUBE_LEN;  // 262144
    const int IMG   = CHANNELS * PLANE;     // 786432

    // ---- batch ALL gather loads; sched_barrier keeps them hoisted ----
    float a00[EQU_COUNT * CHANNELS], a01[EQU_COUNT * CHANNELS];
    float a10[EQU_COUNT * CHANNELS], a11[EQU_COUNT * CHANNELS];
#pragma unroll
    for (int e = 0; e < EQU_COUNT; ++e) {
        const int img_base = (e * 6 + f) * IMG;   // max ~18.1M floats
#pragma unroll
        for (int c = 0; c < CHANNELS; ++c) {
            const float* __restrict__ p = x + img_base + c * PLANE;
            const int i = e * CHANNELS + c;
            a00[i] = p[o00];
            a01[i] = p[o00 + 1];
            a10[i] = p[o10];
            a11[i] = p[o10 + 1];
        }
    }

    // Nothing may be scheduled across this point: all loads stay above.
    __builtin_amdgcn_sched_barrier(0);

    // ---- compute + store ----
    const float w00 = (1.0f - wx) * (1.0f - wy);
    const float w01 = wx * (1.0f - wy);
    const float w10 = (1.0f - wx) * wy;
    const float w11 = wx * wy;

#pragma unroll
    for (int i = 0; i < EQU_COUNT * CHANNELS; ++i) {
        const float val = a00[i] * w00 + a01[i] * w01
                        + a10[i] * w10 + a11[i] * w11;
        __builtin_nontemporal_store(val, &out[i * HW + idx]);
    }
}

extern "C" void kernel_launch(void* const* d_in, const int* in_sizes, int n_in,
                              void* d_out, int out_size, void* d_ws, size_t ws_size,
                              hipStream_t stream) {
    const float* x    = (const float*)d_in[0];
    const float* uv   = (const float*)d_in[1];
    const int*   face = (const int*)d_in[2];
    float*       out  = (float*)d_out;

    const int HW = EQU_H * EQU_W;
    const int block = 256;
    const int grid  = (HW + block - 1) / block;  // 8192 blocks

    hipLaunchKernelGGL(cube2equirec_kernel, dim3(grid), dim3(block), 0, stream,
                       x, uv, face, out);
}